// Round 11
// baseline (206.572 us; speedup 1.0000x reference)
//
#include <hip/hip_runtime.h>
#include <hip/hip_bf16.h>

constexpr int NN = 4096;   // nodes
constexpr int CC = 64;     // channels
constexpr int NH = 4;      // heads
constexpr int DH = 16;     // head dim
constexpr int KSPLIT = 4;  // attention K-dimension split (exact partial sums)
constexpr int KVB = 128;   // attention K/V chunk (columns) per stage

typedef _Float16 f16x4 __attribute__((ext_vector_type(4)));
typedef _Float16 f16x8 __attribute__((ext_vector_type(8)));
typedef float f32x4 __attribute__((ext_vector_type(4)));

// exp(s) = exp2(s*log2e); fold 1/sqrt(Dh)=0.25 and log2e into q.
#define QSCALE 0.36067376022224085f  // 0.25 * log2(e)
#define L2E2   2.8853900817779268f   // 2 * log2(e), for tanh

#if defined(__has_builtin)
#if __has_builtin(__builtin_amdgcn_exp2f)
#define FAST_EXP2(x) __builtin_amdgcn_exp2f(x)
#endif
#if __has_builtin(__builtin_amdgcn_rcpf)
#define FAST_RCP(x) __builtin_amdgcn_rcpf(x)
#endif
#endif
#ifndef FAST_EXP2
#define FAST_EXP2(x) exp2f(x)
#endif
#ifndef FAST_RCP
#define FAST_RCP(x) (1.0f / (x))
#endif

__device__ __forceinline__ float fast_tanh(float x) {
  // tanh(x) = 1 - 2/(exp(2x)+1); exact at +-inf, ~1e-7 abs err elsewhere
  const float t = FAST_EXP2(x * L2E2);
  return fmaf(-2.f, FAST_RCP(t + 1.f), 1.f);
}

// ---------------------------------------------------------------------------
// Fused project + QKV. Per 64-row block: x-tile = inp@Wp^T+bp (K=128), write
// x to global (residual), transpose x-tile into LDS, then qkv = x@Wqkv^T+bqkv
// (K=64, NC=192) with head-split epilogue: q,k f16 [bh][n][16] (q pre-scaled
// QSCALE), v transposed f16 [bh][16][n].
__global__ __launch_bounds__(256) void proj_qkv_k(
    const float* __restrict__ inp, const float* __restrict__ Wp,
    const float* __restrict__ bp, const float* __restrict__ Wqkv,
    const float* __restrict__ bqkv, float* __restrict__ xout,
    _Float16* __restrict__ f16b)
{
  __shared__ __align__(16) float As[64][68];
  __shared__ __align__(16) float Xs[64][68];     // phase A: Wp stage; then x^T
  __shared__ __align__(16) float W2s[64][196];

  const int tid = threadIdx.x;
  const int rowbase = blockIdx.x * 64;
  const int r4 = (tid & 15) * 4;
  const int cg = (tid >> 4) * 4;     // phase A cols
  const int cg2 = (tid >> 4) * 12;   // phase B cols

  // ---- phase A: x = inp @ Wp^T ----
  float acc[4][4];
  #pragma unroll
  for (int i = 0; i < 4; ++i)
    #pragma unroll
    for (int j = 0; j < 4; ++j) acc[i][j] = 0.f;

  for (int k0 = 0; k0 < 128; k0 += 64) {
    if (k0) __syncthreads();
    #pragma unroll
    for (int i = 0; i < 16; ++i) {
      int idx = tid + i * 256;
      int c2 = idx >> 6, kk = idx & 63;
      Xs[kk][c2] = Wp[(size_t)c2 * 128 + k0 + kk];
    }
    #pragma unroll
    for (int i = 0; i < 16; ++i) {
      int idx = tid + i * 256;
      int r = idx >> 6, kk = idx & 63;
      As[kk][r] = inp[(size_t)(rowbase + r) * 128 + k0 + kk];
    }
    __syncthreads();
    #pragma unroll 4
    for (int kk = 0; kk < 64; ++kk) {
      const float4 a = *(const float4*)&As[kk][r4];
      const float4 w4 = *(const float4*)&Xs[kk][cg];
      const float av[4] = {a.x, a.y, a.z, a.w};
      const float wv[4] = {w4.x, w4.y, w4.z, w4.w};
      #pragma unroll
      for (int ri = 0; ri < 4; ++ri)
        #pragma unroll
        for (int ci = 0; ci < 4; ++ci)
          acc[ri][ci] = fmaf(av[ri], wv[ci], acc[ri][ci]);
    }
  }

  float xv[4][4];
  #pragma unroll
  for (int ri = 0; ri < 4; ++ri)
    #pragma unroll
    for (int j = 0; j < 4; ++j) {
      xv[ri][j] = acc[ri][j] + bp[cg + j];
      xout[(size_t)(rowbase + r4 + ri) * CC + cg + j] = xv[ri][j];
    }

  __syncthreads();  // all phase-A LDS reads complete
  #pragma unroll
  for (int ri = 0; ri < 4; ++ri)
    #pragma unroll
    for (int j = 0; j < 4; ++j)
      Xs[cg + j][r4 + ri] = xv[ri][j];   // x^T (k-major for phase B)
  #pragma unroll
  for (int i = 0; i < 48; ++i) {
    int idx = tid + i * 256;
    int c2 = idx >> 6, kk = idx & 63;
    W2s[kk][c2] = Wqkv[(size_t)c2 * 64 + kk];
  }
  __syncthreads();

  // ---- phase B: qkv = x @ Wqkv^T ----
  float acc2[4][12];
  #pragma unroll
  for (int i = 0; i < 4; ++i)
    #pragma unroll
    for (int j = 0; j < 12; ++j) acc2[i][j] = 0.f;

  #pragma unroll 4
  for (int kk = 0; kk < 64; ++kk) {
    const float4 a = *(const float4*)&Xs[kk][r4];
    const float av[4] = {a.x, a.y, a.z, a.w};
    #pragma unroll
    for (int cj = 0; cj < 3; ++cj) {
      const float4 w4 = *(const float4*)&W2s[kk][cg2 + cj * 4];
      const float wv[4] = {w4.x, w4.y, w4.z, w4.w};
      #pragma unroll
      for (int ri = 0; ri < 4; ++ri)
        #pragma unroll
        for (int ci = 0; ci < 4; ++ci)
          acc2[ri][cj * 4 + ci] = fmaf(av[ri], wv[ci], acc2[ri][cj * 4 + ci]);
    }
  }

  #pragma unroll
  for (int ri = 0; ri < 4; ++ri) {
    const int row = rowbase + r4 + ri;
    const int n = row & (NN - 1);
    const int bq = (row >> 12) * NH;
    #pragma unroll
    for (int j = 0; j < 12; ++j) {
      float v = acc2[ri][j] + bqkv[cg2 + j];
      const int c2 = cg2 + j;
      const int which = c2 >> 6;         // 0=q 1=k 2=v
      const int hc = c2 & 63;
      const int bh = bq + (hc >> 4);
      const int d = hc & 15;
      if (which == 0) v *= QSCALE;
      if (which < 2)
        f16b[(size_t)which * 1048576 + ((size_t)bh * NN + n) * DH + d] = (_Float16)v;
      else
        f16b[2097152 + ((size_t)bh * DH + d) * NN + n] = (_Float16)v;
    }
  }
}

// ---------------------------------------------------------------------------
// MFMA flash attention, K-split x4 (f16 in / f32 acc), DOUBLE-BUFFERED
// reg-staged K/V pipeline: per 128-col chunk, issue next chunk's global
// loads into registers BEFORE compute (latency hides under ~8 MFMA sub-
// iters), write to the ping-pong LDS buffer after compute, 1 barrier/chunk.
// Block = 4 waves, same (bh, ks); grid 2048 -> 8 blocks/CU. Writes
// UNNORMALIZED partial O and rowsums (disjoint K-ranges add exactly).
__global__ __launch_bounds__(256, 8) void attn_k(
    const _Float16* __restrict__ qb, const _Float16* __restrict__ kb,
    const _Float16* __restrict__ vtb, float* __restrict__ po,
    float* __restrict__ rs)
{
  __shared__ _Float16 Kl[2][KVB][20];   // [buf][k-row][d] row 40B
  __shared__ _Float16 Vl[2][16][KVB + 8];  // [buf][d][k-col] row 272B

  const int bid = blockIdx.x;            // 0..2047
  const int xcd = bid & 7;
  const int rest = bid >> 3;             // 0..255
  const int bh = 2 * xcd + (rest & 1);   // both bh of an XCD stay local
  const int ks = (rest >> 1) & 3;        // K-split index
  const int n0 = (rest >> 3) * 128;      // q-tile base
  const int tid = threadIdx.x;
  const int w = tid >> 6;
  const int l = tid & 63;
  const int g = l >> 4, i = l & 15;
  const int qbase = n0 + w * 32;
  const int kbeg = ks * (NN / KSPLIT);

  const _Float16* __restrict__ qhp = qb + (size_t)bh * NN * DH;
  const _Float16* __restrict__ khp = kb + (size_t)bh * NN * DH;
  const _Float16* __restrict__ vhp = vtb + (size_t)bh * DH * NN;

  const f16x4 qfA = *(const f16x4*)(qhp + (size_t)(qbase + i) * DH + 4 * g);
  const f16x4 qfB = *(const f16x4*)(qhp + (size_t)(qbase + 16 + i) * DH + 4 * g);

  f32x4 oA = {0.f, 0.f, 0.f, 0.f}, oB = {0.f, 0.f, 0.f, 0.f};
  const f32x4 zz = {0.f, 0.f, 0.f, 0.f};
  float rsA = 0.f, rsB = 0.f;

  // staging maps: one 16B K load + one 16B V load per thread per chunk
  const int sr = tid >> 1, sh = (tid & 1) * 8;      // K: row, half-row
  const int sd = tid >> 4, sc = (tid & 15) * 8;     // V: d-row, col8

  // prologue: stage chunk 0 into buffer 0
  {
    const f16x8 kr = *(const f16x8*)(khp + (size_t)(kbeg + sr) * DH + sh);
    const f16x8 vr = *(const f16x8*)(vhp + (size_t)sd * NN + kbeg + sc);
    *(f16x8*)&Kl[0][sr][sh] = kr;
    *(f16x8*)&Vl[0][sd][sc] = vr;
  }
  __syncthreads();

  constexpr int NCH = (NN / KSPLIT) / KVB;  // 8 chunks
  int cur = 0;
  for (int c = 0; c < NCH; ++c) {
    f16x8 kr, vr;
    if (c + 1 < NCH) {  // issue next chunk's loads early (latency hidden)
      const int nx = kbeg + (c + 1) * KVB;
      kr = *(const f16x8*)(khp + (size_t)(nx + sr) * DH + sh);
      vr = *(const f16x8*)(vhp + (size_t)sd * NN + nx + sc);
    }

    #pragma unroll
    for (int kk = 0; kk < KVB; kk += 16) {
      const f16x4 kf = *(const f16x4*)&Kl[cur][kk + i][4 * g];
      const f16x4 vf = *(const f16x4*)&Vl[cur][i][kk + 4 * g];
      f32x4 sA = __builtin_amdgcn_mfma_f32_16x16x16f16(kf, qfA, zz, 0, 0, 0);
      f32x4 sB = __builtin_amdgcn_mfma_f32_16x16x16f16(kf, qfB, zz, 0, 0, 0);
      const float a0 = FAST_EXP2(sA[0]), a1 = FAST_EXP2(sA[1]),
                  a2 = FAST_EXP2(sA[2]), a3 = FAST_EXP2(sA[3]);
      const float b0 = FAST_EXP2(sB[0]), b1 = FAST_EXP2(sB[1]),
                  b2 = FAST_EXP2(sB[2]), b3 = FAST_EXP2(sB[3]);
      rsA += (a0 + a1) + (a2 + a3);
      rsB += (b0 + b1) + (b2 + b3);
      const auto alo = __builtin_amdgcn_cvt_pkrtz(a0, a1);  // __fp16 x2
      const auto ahi = __builtin_amdgcn_cvt_pkrtz(a2, a3);
      const auto blo = __builtin_amdgcn_cvt_pkrtz(b0, b1);
      const auto bhi = __builtin_amdgcn_cvt_pkrtz(b2, b3);
      f16x4 pA, pB;
      pA[0] = (_Float16)alo[0]; pA[1] = (_Float16)alo[1];
      pA[2] = (_Float16)ahi[0]; pA[3] = (_Float16)ahi[1];
      pB[0] = (_Float16)blo[0]; pB[1] = (_Float16)blo[1];
      pB[2] = (_Float16)bhi[0]; pB[3] = (_Float16)bhi[1];
      oA = __builtin_amdgcn_mfma_f32_16x16x16f16(pA, vf, oA, 0, 0, 0);
      oB = __builtin_amdgcn_mfma_f32_16x16x16f16(pB, vf, oB, 0, 0, 0);
    }

    if (c + 1 < NCH) {
      // safe: buf[cur^1] was last READ in iter c-1; that iter ended with a
      // barrier, so all waves are past those reads before these writes.
      *(f16x8*)&Kl[cur ^ 1][sr][sh] = kr;
      *(f16x8*)&Vl[cur ^ 1][sd][sc] = vr;
    }
    __syncthreads();
    cur ^= 1;
  }

  rsA += __shfl_xor(rsA, 16); rsA += __shfl_xor(rsA, 32);
  rsB += __shfl_xor(rsB, 16); rsB += __shfl_xor(rsB, 32);

  float* __restrict__ pob = po + (size_t)(ks * 16 + bh) * NN * DH;
  #pragma unroll
  for (int r = 0; r < 4; ++r) {
    const int ql = 4 * g + r;
    pob[(size_t)(qbase + ql) * DH + i] = oA[r];
    pob[(size_t)(qbase + 16 + ql) * DH + i] = oB[r];
  }
  if (g == 0) {
    float* __restrict__ rsb = rs + (size_t)(ks * 16 + bh) * NN;
    rsb[qbase + i] = rsA;
    rsb[qbase + 16 + i] = rsB;
  }
}

// ---------------------------------------------------------------------------
// Wo GEMM with fused K-split reduction + residual. A[row][kk] is materialized
// in LDS staging directly from po/rs partials: of = (sum_ks po) / (sum_ks rs).
// pre2 = of @ Wo^T + bo + x.  po ks-stride = 16*4096*16 = 1048576 floats.
__global__ __launch_bounds__(256) void wo_red_k(
    const float* __restrict__ po, const float* __restrict__ rs,
    const float* __restrict__ Wo, const float* __restrict__ bo,
    const float* __restrict__ xin, float* __restrict__ out)
{
  __shared__ __align__(16) float As[64][68];
  __shared__ __align__(16) float Ws[64][68];
  __shared__ float Linv[64][4];

  const int tid = threadIdx.x;
  const int rowbase = blockIdx.x * 64;
  const int r4 = (tid & 15) * 4;
  const int cg = (tid >> 4) * 4;

  // per-(row, head) inverse denominators
  {
    const int r = tid & 63, hb = tid >> 6;
    const int row = rowbase + r;
    const int bh = (row >> 12) * NH + hb;
    const int n = row & (NN - 1);
    const float s = rs[(size_t)bh * NN + n] + rs[(size_t)(16 + bh) * NN + n] +
                    rs[(size_t)(32 + bh) * NN + n] + rs[(size_t)(48 + bh) * NN + n];
    Linv[r][hb] = 1.f / s;
  }
  // stage Wo
  #pragma unroll
  for (int i = 0; i < 16; ++i) {
    int idx = tid + i * 256;
    int c2 = idx >> 6, kk = idx & 63;
    Ws[kk][c2] = Wo[(size_t)c2 * 64 + kk];
  }
  __syncthreads();
  // stage A = reduced+normalized attention output
  #pragma unroll
  for (int i = 0; i < 16; ++i) {
    int idx = tid + i * 256;
    int r = idx >> 6, kk = idx & 63;
    const int row = rowbase + r;
    const int bh = (row >> 12) * NH + (kk >> 4);
    const int n = row & (NN - 1);
    const int d = kk & 15;
    const size_t base = (((size_t)bh * NN + n) * DH) + d;
    const float v = po[base] + po[base + 1048576] +
                    po[base + 2097152] + po[base + 3145728];
    As[kk][r] = v * Linv[r][kk >> 4];
  }
  __syncthreads();

  float acc[4][4];
  #pragma unroll
  for (int i = 0; i < 4; ++i)
    #pragma unroll
    for (int j = 0; j < 4; ++j) acc[i][j] = 0.f;

  #pragma unroll 4
  for (int kk = 0; kk < 64; ++kk) {
    const float4 a = *(const float4*)&As[kk][r4];
    const float4 w4 = *(const float4*)&Ws[kk][cg];
    const float av[4] = {a.x, a.y, a.z, a.w};
    const float wv[4] = {w4.x, w4.y, w4.z, w4.w};
    #pragma unroll
    for (int ri = 0; ri < 4; ++ri)
      #pragma unroll
      for (int ci = 0; ci < 4; ++ci)
        acc[ri][ci] = fmaf(av[ri], wv[ci], acc[ri][ci]);
  }

  #pragma unroll
  for (int ri = 0; ri < 4; ++ri) {
    const int row = rowbase + r4 + ri;
    #pragma unroll
    for (int j = 0; j < 4; ++j) {
      const int c = cg + j;
      out[(size_t)row * CC + c] =
          acc[ri][j] + bo[c] + xin[(size_t)row * CC + c];
    }
  }
}

// ---------------------------------------------------------------------------
// Fused MLP: t = relu(h @ W1^T + b1) (kept in LDS), pre3 = t @ W2^T + b2m + h.
__global__ __launch_bounds__(256) void mlp_k(
    const float* __restrict__ hf, const float* __restrict__ W1,
    const float* __restrict__ b1, const float* __restrict__ W2,
    const float* __restrict__ b2m, float* __restrict__ out)
{
  __shared__ __align__(16) float As[64][68];     // h^T tile (k-major)
  __shared__ __align__(16) float Wbuf[8704];     // W1 [64][132] then W2 [128][68]
  __shared__ __align__(16) float Ts[128][68];    // relu(t)^T

  const int tid = threadIdx.x;
  const int rowbase = blockIdx.x * 64;
  const int r4 = (tid & 15) * 4;
  const int cg8 = (tid >> 4) * 8;    // phase 1 cols (128/16)
  const int cg4 = (tid >> 4) * 4;    // phase 2 cols (64/16)

  // stage h tile + W1
  #pragma unroll
  for (int i = 0; i < 32; ++i) {
    int idx = tid + i * 256;          // 8192 = 128c x 64k
    int c2 = idx >> 6, kk = idx & 63;
    Wbuf[kk * 132 + c2] = W1[(size_t)c2 * 64 + kk];
  }
  #pragma unroll
  for (int i = 0; i < 16; ++i) {
    int idx = tid + i * 256;
    int r = idx >> 6, kk = idx & 63;
    As[kk][r] = hf[(size_t)(rowbase + r) * CC + kk];
  }
  __syncthreads();

  // phase 1: t = relu(h @ W1^T + b1)
  float acc1[4][8];
  #pragma unroll
  for (int i = 0; i < 4; ++i)
    #pragma unroll
    for (int j = 0; j < 8; ++j) acc1[i][j] = 0.f;

  #pragma unroll 4
  for (int kk = 0; kk < 64; ++kk) {
    const float4 a = *(const float4*)&As[kk][r4];
    const float av[4] = {a.x, a.y, a.z, a.w};
    #pragma unroll
    for (int cj = 0; cj < 2; ++cj) {
      const float4 w4 = *(const float4*)&Wbuf[kk * 132 + cg8 + cj * 4];
      const float wv[4] = {w4.x, w4.y, w4.z, w4.w};
      #pragma unroll
      for (int ri = 0; ri < 4; ++ri)
        #pragma unroll
        for (int ci = 0; ci < 4; ++ci)
          acc1[ri][cj * 4 + ci] = fmaf(av[ri], wv[ci], acc1[ri][cj * 4 + ci]);
    }
  }
  #pragma unroll
  for (int ri = 0; ri < 4; ++ri)
    #pragma unroll
    for (int j = 0; j < 8; ++j)
      Ts[cg8 + j][r4 + ri] = fmaxf(acc1[ri][j] + b1[cg8 + j], 0.f);
  __syncthreads();

  // stage W2 over W1
  #pragma unroll
  for (int i = 0; i < 32; ++i) {
    int idx = tid + i * 256;          // 8192 = 64c x 128k
    int c2 = idx >> 7, kk = idx & 127;
    Wbuf[kk * 68 + c2] = W2[(size_t)c2 * 128 + kk];
  }
  __syncthreads();

  // phase 2: pre3 = t @ W2^T + b2m + h
  float acc2[4][4];
  #pragma unroll
  for (int i = 0; i < 4; ++i)
    #pragma unroll
    for (int j = 0; j < 4; ++j) acc2[i][j] = 0.f;

  #pragma unroll 4
  for (int kk = 0; kk < 128; ++kk) {
    const float4 a = *(const float4*)&Ts[kk][r4];
    const float4 w4 = *(const float4*)&Wbuf[kk * 68 + cg4];
    const float av[4] = {a.x, a.y, a.z, a.w};
    const float wv[4] = {w4.x, w4.y, w4.z, w4.w};
    #pragma unroll
    for (int ri = 0; ri < 4; ++ri)
      #pragma unroll
      for (int ci = 0; ci < 4; ++ci)
        acc2[ri][ci] = fmaf(av[ri], wv[ci], acc2[ri][ci]);
  }

  #pragma unroll
  for (int ri = 0; ri < 4; ++ri) {
    const int row = rowbase + r4 + ri;
    #pragma unroll
    for (int j = 0; j < 4; ++j) {
      const int c = cg4 + j;
      out[(size_t)row * CC + c] = acc2[ri][j] + b2m[c] + As[c][r4 + ri];
    }
  }
}

// ---------------------------------------------------------------------------
// BatchNorm over node axis, 4 channels per block (float4), biased var,
// EPS=1e-5, optional fused tanh. Grid 64 = 4 b x 16 channel-quads.
// In-place safe (each thread rewrites only elements it re-reads itself).
__global__ __launch_bounds__(256) void bn4_k(
    const float* __restrict__ in, const float* __restrict__ g,
    const float* __restrict__ b, float* __restrict__ out, int do_tanh)
{
  const int bb = blockIdx.x >> 4;
  const int c4 = (blockIdx.x & 15) * 4;
  const float* __restrict__ base = in + (size_t)bb * NN * CC + c4;
  const int tid = threadIdx.x;

  float4 s = {0, 0, 0, 0}, sq = {0, 0, 0, 0};
  #pragma unroll
  for (int i = 0; i < 16; ++i) {
    const float4 v = *(const float4*)&base[(size_t)(tid + i * 256) * CC];
    s.x += v.x; s.y += v.y; s.z += v.z; s.w += v.w;
    sq.x = fmaf(v.x, v.x, sq.x); sq.y = fmaf(v.y, v.y, sq.y);
    sq.z = fmaf(v.z, v.z, sq.z); sq.w = fmaf(v.w, v.w, sq.w);
  }
  #pragma unroll
  for (int off = 32; off; off >>= 1) {
    s.x += __shfl_down(s.x, off); s.y += __shfl_down(s.y, off);
    s.z += __shfl_down(s.z, off); s.w += __shfl_down(s.w, off);
    sq.x += __shfl_down(sq.x, off); sq.y += __shfl_down(sq.y, off);
    sq.z += __shfl_down(sq.z, off); sq.w += __shfl_down(sq.w, off);
  }
  __shared__ float red[4][8];
  const int wv = tid >> 6;
  if ((tid & 63) == 0) {
    red[wv][0] = s.x; red[wv][1] = s.y; red[wv][2] = s.z; red[wv][3] = s.w;
    red[wv][4] = sq.x; red[wv][5] = sq.y; red[wv][6] = sq.z; red[wv][7] = sq.w;
  }
  __syncthreads();
  float scale[4], shift[4];
  #pragma unroll
  for (int j = 0; j < 4; ++j) {
    const float ts = red[0][j] + red[1][j] + red[2][j] + red[3][j];
    const float tq = red[0][4 + j] + red[1][4 + j] + red[2][4 + j] + red[3][4 + j];
    const float mean = ts * (1.f / NN);
    const float var = tq * (1.f / NN) - mean * mean;
    const float rstd = rsqrtf(var + 1e-5f);
    scale[j] = g[c4 + j] * rstd;
    shift[j] = b[c4 + j] - mean * scale[j];
  }
  float* __restrict__ ob = out + (size_t)bb * NN * CC + c4;
  #pragma unroll
  for (int i = 0; i < 16; ++i) {
    const size_t idx = (size_t)(tid + i * 256) * CC;
    const float4 v = *(const float4*)&base[idx];
    float4 o;
    o.x = v.x * scale[0] + shift[0];
    o.y = v.y * scale[1] + shift[1];
    o.z = v.z * scale[2] + shift[2];
    o.w = v.w * scale[3] + shift[3];
    if (do_tanh) {
      o.x = fast_tanh(o.x); o.y = fast_tanh(o.y);
      o.z = fast_tanh(o.z); o.w = fast_tanh(o.w);
    }
    *(float4*)&ob[idx] = o;
  }
}

// ---------------------------------------------------------------------------
extern "C" void kernel_launch(void* const* d_in, const int* in_sizes, int n_in,
                              void* d_out, int out_size, void* d_ws, size_t ws_size,
                              hipStream_t stream)
{
  const float* inp  = (const float*)d_in[0];
  const float* Wp   = (const float*)d_in[2];
  const float* bp   = (const float*)d_in[3];
  const float* Wqkv = (const float*)d_in[4];
  const float* bqkv = (const float*)d_in[5];
  const float* Wo   = (const float*)d_in[6];
  const float* bo   = (const float*)d_in[7];
  const float* g2   = (const float*)d_in[8];
  const float* b2   = (const float*)d_in[9];
  const float* W1   = (const float*)d_in[10];
  const float* b1   = (const float*)d_in[11];
  const float* W2   = (const float*)d_in[12];
  const float* b2m  = (const float*)d_in[13];
  const float* g3   = (const float*)d_in[14];
  const float* b3   = (const float*)d_in[15];

  float* w = (float*)d_ws;
  float* x    = w;                 // [16384][64]   (dead after wo_red)
  float* qkvA = w + 1048576;       // f16 arena: q 0..1M, k 1M..2M, vt 2M..3M halves
  float* hf   = w + 2621440;       // pre2 -> (in-place bn) h
  float* pf   = w + 3670016;       // pre3 = h + mlp
  float* poW  = w + 4718592;       // attn partial O [4][16][4096][16]
  float* rsW  = w + 8912896;       // attn partial rowsums [4][16][4096]

  _Float16* f16b = (_Float16*)qkvA;

  proj_qkv_k<<<dim3(256), dim3(256), 0, stream>>>(inp, Wp, bp, Wqkv, bqkv, x, f16b);
  attn_k<<<dim3(2048), dim3(256), 0, stream>>>(f16b, f16b + 1048576,
                                               f16b + 2097152, poW, rsW);
  wo_red_k<<<dim3(256), dim3(256), 0, stream>>>(poW, rsW, Wo, bo, x, hf);
  bn4_k<<<dim3(64), dim3(256), 0, stream>>>(hf, g2, b2, hf, 0);
  mlp_k<<<dim3(256), dim3(256), 0, stream>>>(hf, W1, b1, W2, b2m, pf);
  bn4_k<<<dim3(64), dim3(256), 0, stream>>>(pf, g3, b3, (float*)d_out, 1);
}

// Round 13
// 192.328 us; speedup vs baseline: 1.0741x; 1.0741x over previous
//
#include <hip/hip_runtime.h>
#include <hip/hip_bf16.h>

constexpr int NN = 4096;   // nodes
constexpr int CC = 64;     // channels
constexpr int NH = 4;      // heads
constexpr int DH = 16;     // head dim
constexpr int KSPLIT = 4;  // attention K-dimension split (exact partial sums)

typedef _Float16 f16x4 __attribute__((ext_vector_type(4)));
typedef float f32x4 __attribute__((ext_vector_type(4)));

#define QSCALE 0.36067376022224085f  // 0.25 * log2(e)
#define L2E2   2.8853900817779268f   // 2 * log2(e), for tanh

#if defined(__has_builtin)
#if __has_builtin(__builtin_amdgcn_exp2f)
#define FAST_EXP2(x) __builtin_amdgcn_exp2f(x)
#endif
#if __has_builtin(__builtin_amdgcn_rcpf)
#define FAST_RCP(x) __builtin_amdgcn_rcpf(x)
#endif
#endif
#ifndef FAST_EXP2
#define FAST_EXP2(x) exp2f(x)
#endif
#ifndef FAST_RCP
#define FAST_RCP(x) (1.0f / (x))
#endif

__device__ __forceinline__ float fast_tanh(float x) {
  const float t = FAST_EXP2(x * L2E2);
  return fmaf(-2.f, FAST_RCP(t + 1.f), 1.f);
}

// ---------------------------------------------------------------------------
// Fused project + QKV, 16-row tiles, grid 1024 (4 blocks/CU, 16 waves/CU).
// No A/W LDS staging: A rows and W rows read direct from global (L1/L2-hot).
// Thread = (r = tid&15, cg = tid>>4). x-tile in LDS (4.3 KB).
__global__ __launch_bounds__(256, 4) void proj_qkv_k(
    const float* __restrict__ inp, const float* __restrict__ Wp,
    const float* __restrict__ bp, const float* __restrict__ Wqkv,
    const float* __restrict__ bqkv, float* __restrict__ xout,
    _Float16* __restrict__ f16b)
{
  __shared__ __align__(16) float Xs[16][68];

  const int tid = threadIdx.x;
  const int rowbase = blockIdx.x * 16;
  const int r = tid & 15;
  const int cg = tid >> 4;
  const int row = rowbase + r;

  // ---- phase A: x[r][cg*4..+3] = inp row . Wp rows ----
  float acc[4] = {0.f, 0.f, 0.f, 0.f};
  const float* arow = inp + (size_t)row * 128;
  #pragma unroll 8
  for (int k = 0; k < 128; k += 4) {
    const float4 a = *(const float4*)(arow + k);
    #pragma unroll
    for (int ci = 0; ci < 4; ++ci) {
      const float4 w = *(const float4*)(Wp + (size_t)(cg * 4 + ci) * 128 + k);
      acc[ci] = fmaf(a.x, w.x, fmaf(a.y, w.y, fmaf(a.z, w.z, fmaf(a.w, w.w, acc[ci]))));
    }
  }
  #pragma unroll
  for (int ci = 0; ci < 4; ++ci) {
    const float v = acc[ci] + bp[cg * 4 + ci];
    xout[(size_t)row * CC + cg * 4 + ci] = v;
    Xs[r][cg * 4 + ci] = v;
  }
  __syncthreads();

  // ---- phase B: qkv[r][cg*12..+11] = x row . Wqkv rows ----
  float acc2[12];
  #pragma unroll
  for (int j = 0; j < 12; ++j) acc2[j] = 0.f;
  const int cg2 = cg * 12;
  #pragma unroll 4
  for (int k = 0; k < 64; k += 4) {
    const float4 a = *(const float4*)&Xs[r][k];
    #pragma unroll
    for (int j = 0; j < 12; ++j) {
      const float4 w = *(const float4*)(Wqkv + (size_t)(cg2 + j) * 64 + k);
      acc2[j] = fmaf(a.x, w.x, fmaf(a.y, w.y, fmaf(a.z, w.z, fmaf(a.w, w.w, acc2[j]))));
    }
  }

  const int n = row & (NN - 1);
  const int bq = (row >> 12) * NH;
  #pragma unroll
  for (int j = 0; j < 12; ++j) {
    float v = acc2[j] + bqkv[cg2 + j];
    const int c2 = cg2 + j;
    const int which = c2 >> 6;         // 0=q 1=k 2=v
    const int hc = c2 & 63;
    const int bh = bq + (hc >> 4);
    const int d = hc & 15;
    if (which == 0) v *= QSCALE;
    if (which < 2)
      f16b[(size_t)which * 1048576 + ((size_t)bh * NN + n) * DH + d] = (_Float16)v;
    else
      f16b[2097152 + ((size_t)bh * DH + d) * NN + n] = (_Float16)v;
  }
}

// ---------------------------------------------------------------------------
// MFMA flash attention, K-split x4 (f16 in / f32 acc), LDS-staged K/V.
// (round-10 version, verbatim — known-good)
__global__ __launch_bounds__(256, 8) void attn_k(
    const _Float16* __restrict__ qb, const _Float16* __restrict__ kb,
    const _Float16* __restrict__ vtb, float* __restrict__ po,
    float* __restrict__ rs)
{
  __shared__ _Float16 Kl[64][20];   // [k-row][d], row 40B
  __shared__ _Float16 Vl[16][72];   // [d][k-col], row 144B

  const int bid = blockIdx.x;            // 0..2047
  const int xcd = bid & 7;
  const int rest = bid >> 3;             // 0..255
  const int bh = 2 * xcd + (rest & 1);   // both bh of an XCD stay local
  const int ks = (rest >> 1) & 3;        // K-split index
  const int n0 = (rest >> 3) * 128;      // q-tile base
  const int tid = threadIdx.x;
  const int w = tid >> 6;
  const int l = tid & 63;
  const int g = l >> 4, i = l & 15;
  const int qbase = n0 + w * 32;
  const int kbeg = ks * (NN / KSPLIT);
  const int kend = kbeg + NN / KSPLIT;

  const _Float16* __restrict__ qhp = qb + (size_t)bh * NN * DH;
  const _Float16* __restrict__ khp = kb + (size_t)bh * NN * DH;
  const _Float16* __restrict__ vhp = vtb + (size_t)bh * DH * NN;

  const f16x4 qfA = *(const f16x4*)(qhp + (size_t)(qbase + i) * DH + 4 * g);
  const f16x4 qfB = *(const f16x4*)(qhp + (size_t)(qbase + 16 + i) * DH + 4 * g);

  f32x4 oA = {0.f, 0.f, 0.f, 0.f}, oB = {0.f, 0.f, 0.f, 0.f};
  const f32x4 zz = {0.f, 0.f, 0.f, 0.f};
  float rsA = 0.f, rsB = 0.f;

  const int srow = tid >> 2, spart = tid & 3;       // K staging map
  const int sd = tid >> 4, scol = (tid & 15) * 4;   // V staging map

  for (int c0 = kbeg; c0 < kend; c0 += 64) {
    __syncthreads();
    *(f16x4*)&Kl[srow][spart * 4] =
        *(const f16x4*)(khp + (size_t)(c0 + srow) * DH + spart * 4);
    *(f16x4*)&Vl[sd][scol] =
        *(const f16x4*)(vhp + (size_t)sd * NN + c0 + scol);
    __syncthreads();

    #pragma unroll
    for (int kk = 0; kk < 64; kk += 16) {
      const f16x4 kf = *(const f16x4*)&Kl[kk + i][4 * g];
      const f16x4 vf = *(const f16x4*)&Vl[i][kk + 4 * g];
      f32x4 sA = __builtin_amdgcn_mfma_f32_16x16x16f16(kf, qfA, zz, 0, 0, 0);
      f32x4 sB = __builtin_amdgcn_mfma_f32_16x16x16f16(kf, qfB, zz, 0, 0, 0);
      const float a0 = FAST_EXP2(sA[0]), a1 = FAST_EXP2(sA[1]),
                  a2 = FAST_EXP2(sA[2]), a3 = FAST_EXP2(sA[3]);
      const float b0 = FAST_EXP2(sB[0]), b1 = FAST_EXP2(sB[1]),
                  b2 = FAST_EXP2(sB[2]), b3 = FAST_EXP2(sB[3]);
      rsA += (a0 + a1) + (a2 + a3);
      rsB += (b0 + b1) + (b2 + b3);
      const auto alo = __builtin_amdgcn_cvt_pkrtz(a0, a1);  // __fp16 x2
      const auto ahi = __builtin_amdgcn_cvt_pkrtz(a2, a3);
      const auto blo = __builtin_amdgcn_cvt_pkrtz(b0, b1);
      const auto bhi = __builtin_amdgcn_cvt_pkrtz(b2, b3);
      f16x4 pA, pB;
      pA[0] = (_Float16)alo[0]; pA[1] = (_Float16)alo[1];
      pA[2] = (_Float16)ahi[0]; pA[3] = (_Float16)ahi[1];
      pB[0] = (_Float16)blo[0]; pB[1] = (_Float16)blo[1];
      pB[2] = (_Float16)bhi[0]; pB[3] = (_Float16)bhi[1];
      oA = __builtin_amdgcn_mfma_f32_16x16x16f16(pA, vf, oA, 0, 0, 0);
      oB = __builtin_amdgcn_mfma_f32_16x16x16f16(pB, vf, oB, 0, 0, 0);
    }
  }

  rsA += __shfl_xor(rsA, 16); rsA += __shfl_xor(rsA, 32);
  rsB += __shfl_xor(rsB, 16); rsB += __shfl_xor(rsB, 32);

  float* __restrict__ pob = po + (size_t)(ks * 16 + bh) * NN * DH;
  #pragma unroll
  for (int r = 0; r < 4; ++r) {
    const int ql = 4 * g + r;
    pob[(size_t)(qbase + ql) * DH + i] = oA[r];
    pob[(size_t)(qbase + 16 + ql) * DH + i] = oB[r];
  }
  if (g == 0) {
    float* __restrict__ rsb = rs + (size_t)(ks * 16 + bh) * NN;
    rsb[qbase + i] = rsA;
    rsb[qbase + 16 + i] = rsB;
  }
}

// ---------------------------------------------------------------------------
// Wo GEMM + fused K-split reduction + residual, 16-row tiles, grid 1024.
// po ks-stride = 16*4096*16 = 1048576 floats; rs ks-stride = 16*4096 = 65536.
__global__ __launch_bounds__(256, 4) void wo_red_k(
    const float* __restrict__ po, const float* __restrict__ rs,
    const float* __restrict__ Wo, const float* __restrict__ bo,
    const float* __restrict__ xin, float* __restrict__ out)
{
  __shared__ __align__(16) float Xs[16][68];

  const int tid = threadIdx.x;
  const int rowbase = blockIdx.x * 16;

  // stage of-tile: thread t -> row t>>4, cols (t&15)*4..+3
  {
    const int r = tid >> 4, kk4 = (tid & 15) * 4;
    const int row = rowbase + r;
    const int n = row & (NN - 1);
    const int bh = (row >> 12) * NH + (kk4 >> 4);
    const int d0 = kk4 & 15;
    const size_t base = ((size_t)bh * NN + n) * DH + d0;
    const float4 p0 = *(const float4*)(po + base);
    const float4 p1 = *(const float4*)(po + base + 1048576);
    const float4 p2 = *(const float4*)(po + base + 2097152);
    const float4 p3 = *(const float4*)(po + base + 3145728);
    const size_t rb = (size_t)bh * NN + n;
    const float sden = rs[rb] + rs[rb + 65536] + rs[rb + 131072] + rs[rb + 196608];
    const float inv = 1.f / sden;
    Xs[r][kk4 + 0] = (p0.x + p1.x + p2.x + p3.x) * inv;
    Xs[r][kk4 + 1] = (p0.y + p1.y + p2.y + p3.y) * inv;
    Xs[r][kk4 + 2] = (p0.z + p1.z + p2.z + p3.z) * inv;
    Xs[r][kk4 + 3] = (p0.w + p1.w + p2.w + p3.w) * inv;
  }
  __syncthreads();

  const int r = tid & 15;
  const int cg = tid >> 4;
  const int row = rowbase + r;
  float acc[4] = {0.f, 0.f, 0.f, 0.f};
  #pragma unroll 4
  for (int k = 0; k < 64; k += 4) {
    const float4 a = *(const float4*)&Xs[r][k];
    #pragma unroll
    for (int ci = 0; ci < 4; ++ci) {
      const float4 w = *(const float4*)(Wo + (size_t)(cg * 4 + ci) * 64 + k);
      acc[ci] = fmaf(a.x, w.x, fmaf(a.y, w.y, fmaf(a.z, w.z, fmaf(a.w, w.w, acc[ci]))));
    }
  }
  #pragma unroll
  for (int ci = 0; ci < 4; ++ci) {
    const int c = cg * 4 + ci;
    out[(size_t)row * CC + c] = acc[ci] + bo[c] + xin[(size_t)row * CC + c];
  }
}

// ---------------------------------------------------------------------------
// Fused MLP, 16-row tiles, grid 1024: t = relu(h @ W1^T + b1) (LDS, 8.4 KB),
// pre3 = t @ W2^T + b2m + h.
__global__ __launch_bounds__(256, 4) void mlp_k(
    const float* __restrict__ hf, const float* __restrict__ W1,
    const float* __restrict__ b1, const float* __restrict__ W2,
    const float* __restrict__ b2m, float* __restrict__ out)
{
  __shared__ __align__(16) float Ts[16][132];

  const int tid = threadIdx.x;
  const int rowbase = blockIdx.x * 16;
  const int r = tid & 15;
  const int cg = tid >> 4;
  const int row = rowbase + r;
  const float* hrow = hf + (size_t)row * CC;

  // phase 1: t[r][cg*8..+7]
  float acc1[8];
  #pragma unroll
  for (int j = 0; j < 8; ++j) acc1[j] = 0.f;
  const int cg8 = cg * 8;
  #pragma unroll 4
  for (int k = 0; k < 64; k += 4) {
    const float4 a = *(const float4*)(hrow + k);
    #pragma unroll
    for (int j = 0; j < 8; ++j) {
      const float4 w = *(const float4*)(W1 + (size_t)(cg8 + j) * 64 + k);
      acc1[j] = fmaf(a.x, w.x, fmaf(a.y, w.y, fmaf(a.z, w.z, fmaf(a.w, w.w, acc1[j]))));
    }
  }
  #pragma unroll
  for (int j = 0; j < 8; ++j)
    Ts[r][cg8 + j] = fmaxf(acc1[j] + b1[cg8 + j], 0.f);
  __syncthreads();

  // phase 2: out[r][cg*4..+3] = t row . W2 rows + b2m + h
  float acc2[4] = {0.f, 0.f, 0.f, 0.f};
  #pragma unroll 4
  for (int k = 0; k < 128; k += 4) {
    const float4 a = *(const float4*)&Ts[r][k];
    #pragma unroll
    for (int ci = 0; ci < 4; ++ci) {
      const float4 w = *(const float4*)(W2 + (size_t)(cg * 4 + ci) * 128 + k);
      acc2[ci] = fmaf(a.x, w.x, fmaf(a.y, w.y, fmaf(a.z, w.z, fmaf(a.w, w.w, acc2[ci]))));
    }
  }
  #pragma unroll
  for (int ci = 0; ci < 4; ++ci) {
    const int c = cg * 4 + ci;
    out[(size_t)row * CC + c] = acc2[ci] + b2m[c] + hrow[c];
  }
}

// ---------------------------------------------------------------------------
// BatchNorm over node axis, 4 channels per block (float4), biased var,
// EPS=1e-5, optional fused tanh. Grid 64. In-place safe.
__global__ __launch_bounds__(256) void bn4_k(
    const float* __restrict__ in, const float* __restrict__ g,
    const float* __restrict__ b, float* __restrict__ out, int do_tanh)
{
  const int bb = blockIdx.x >> 4;
  const int c4 = (blockIdx.x & 15) * 4;
  const float* __restrict__ base = in + (size_t)bb * NN * CC + c4;
  const int tid = threadIdx.x;

  float4 s = {0, 0, 0, 0}, sq = {0, 0, 0, 0};
  #pragma unroll
  for (int i = 0; i < 16; ++i) {
    const float4 v = *(const float4*)&base[(size_t)(tid + i * 256) * CC];
    s.x += v.x; s.y += v.y; s.z += v.z; s.w += v.w;
    sq.x = fmaf(v.x, v.x, sq.x); sq.y = fmaf(v.y, v.y, sq.y);
    sq.z = fmaf(v.z, v.z, sq.z); sq.w = fmaf(v.w, v.w, sq.w);
  }
  #pragma unroll
  for (int off = 32; off; off >>= 1) {
    s.x += __shfl_down(s.x, off); s.y += __shfl_down(s.y, off);
    s.z += __shfl_down(s.z, off); s.w += __shfl_down(s.w, off);
    sq.x += __shfl_down(sq.x, off); sq.y += __shfl_down(sq.y, off);
    sq.z += __shfl_down(sq.z, off); sq.w += __shfl_down(sq.w, off);
  }
  __shared__ float red[4][8];
  const int wv = tid >> 6;
  if ((tid & 63) == 0) {
    red[wv][0] = s.x; red[wv][1] = s.y; red[wv][2] = s.z; red[wv][3] = s.w;
    red[wv][4] = sq.x; red[wv][5] = sq.y; red[wv][6] = sq.z; red[wv][7] = sq.w;
  }
  __syncthreads();
  float scale[4], shift[4];
  #pragma unroll
  for (int j = 0; j < 4; ++j) {
    const float ts = red[0][j] + red[1][j] + red[2][j] + red[3][j];
    const float tq = red[0][4 + j] + red[1][4 + j] + red[2][4 + j] + red[3][4 + j];
    const float mean = ts * (1.f / NN);
    const float var = tq * (1.f / NN) - mean * mean;
    const float rstd = rsqrtf(var + 1e-5f);
    scale[j] = g[c4 + j] * rstd;
    shift[j] = b[c4 + j] - mean * scale[j];
  }
  float* __restrict__ ob = out + (size_t)bb * NN * CC + c4;
  #pragma unroll
  for (int i = 0; i < 16; ++i) {
    const size_t idx = (size_t)(tid + i * 256) * CC;
    const float4 v = *(const float4*)&base[idx];
    float4 o;
    o.x = v.x * scale[0] + shift[0];
    o.y = v.y * scale[1] + shift[1];
    o.z = v.z * scale[2] + shift[2];
    o.w = v.w * scale[3] + shift[3];
    if (do_tanh) {
      o.x = fast_tanh(o.x); o.y = fast_tanh(o.y);
      o.z = fast_tanh(o.z); o.w = fast_tanh(o.w);
    }
    *(float4*)&ob[idx] = o;
  }
}

// ---------------------------------------------------------------------------
extern "C" void kernel_launch(void* const* d_in, const int* in_sizes, int n_in,
                              void* d_out, int out_size, void* d_ws, size_t ws_size,
                              hipStream_t stream)
{
  const float* inp  = (const float*)d_in[0];
  const float* Wp   = (const float*)d_in[2];
  const float* bp   = (const float*)d_in[3];
  const float* Wqkv = (const float*)d_in[4];
  const float* bqkv = (const float*)d_in[5];
  const float* Wo   = (const float*)d_in[6];
  const float* bo   = (const float*)d_in[7];
  const float* g2   = (const float*)d_in[8];
  const float* b2   = (const float*)d_in[9];
  const float* W1   = (const float*)d_in[10];
  const float* b1   = (const float*)d_in[11];
  const float* W2   = (const float*)d_in[12];
  const float* b2m  = (const float*)d_in[13];
  const float* g3   = (const float*)d_in[14];
  const float* b3   = (const float*)d_in[15];

  float* w = (float*)d_ws;
  float* x    = w;                 // [16384][64]   (dead after wo_red)
  float* qkvA = w + 1048576;       // f16 arena: q 0..1M, k 1M..2M, vt 2M..3M halves
  float* hf   = w + 2621440;       // pre2 -> (in-place bn) h
  float* pf   = w + 3670016;       // pre3 = h + mlp
  float* poW  = w + 4718592;       // attn partial O [4][16][4096][16]
  float* rsW  = w + 8912896;       // attn partial rowsums [4][16][4096]

  _Float16* f16b = (_Float16*)qkvA;

  proj_qkv_k<<<dim3(1024), dim3(256), 0, stream>>>(inp, Wp, bp, Wqkv, bqkv, x, f16b);
  attn_k<<<dim3(2048), dim3(256), 0, stream>>>(f16b, f16b + 1048576,
                                               f16b + 2097152, poW, rsW);
  wo_red_k<<<dim3(1024), dim3(256), 0, stream>>>(poW, rsW, Wo, bo, x, hf);
  bn4_k<<<dim3(64), dim3(256), 0, stream>>>(hf, g2, b2, hf, 0);
  mlp_k<<<dim3(1024), dim3(256), 0, stream>>>(hf, W1, b1, W2, b2m, pf);
  bn4_k<<<dim3(64), dim3(256), 0, stream>>>(pf, g3, b3, (float*)d_out, 1);
}

// Round 15
// 125.654 us; speedup vs baseline: 1.6440x; 1.5306x over previous
//
#include <hip/hip_runtime.h>
#include <hip/hip_bf16.h>

constexpr int NN = 4096;   // nodes
constexpr int CC = 64;     // channels
constexpr int NH = 4;      // heads
constexpr int DH = 16;     // head dim
constexpr int KSPLIT = 4;  // attention K-dimension split (exact partial sums)

typedef _Float16 f16x4 __attribute__((ext_vector_type(4)));
typedef float f32x4 __attribute__((ext_vector_type(4)));

#define QSCALE 0.36067376022224085f  // 0.25 * log2(e)
#define L2E2   2.8853900817779268f   // 2 * log2(e), for tanh

#if defined(__has_builtin)
#if __has_builtin(__builtin_amdgcn_exp2f)
#define FAST_EXP2(x) __builtin_amdgcn_exp2f(x)
#endif
#if __has_builtin(__builtin_amdgcn_rcpf)
#define FAST_RCP(x) __builtin_amdgcn_rcpf(x)
#endif
#endif
#ifndef FAST_EXP2
#define FAST_EXP2(x) exp2f(x)
#endif
#ifndef FAST_RCP
#define FAST_RCP(x) (1.0f / (x))
#endif

__device__ __forceinline__ float fast_tanh(float x) {
  const float t = FAST_EXP2(x * L2E2);
  return fmaf(-2.f, FAST_RCP(t + 1.f), 1.f);
}

// ---------------------------------------------------------------------------
// Fused project + QKV (round-10 known-good). Per 64-row block: x-tile =
// inp@Wp^T+bp (K=128, LDS-staged), write x to global, transpose x-tile into
// LDS, qkv = x@Wqkv^T+bqkv with head-split f16 epilogue.
__global__ __launch_bounds__(256) void proj_qkv_k(
    const float* __restrict__ inp, const float* __restrict__ Wp,
    const float* __restrict__ bp, const float* __restrict__ Wqkv,
    const float* __restrict__ bqkv, float* __restrict__ xout,
    _Float16* __restrict__ f16b)
{
  __shared__ __align__(16) float As[64][68];
  __shared__ __align__(16) float Xs[64][68];
  __shared__ __align__(16) float W2s[64][196];

  const int tid = threadIdx.x;
  const int rowbase = blockIdx.x * 64;
  const int r4 = (tid & 15) * 4;
  const int cg = (tid >> 4) * 4;
  const int cg2 = (tid >> 4) * 12;

  float acc[4][4];
  #pragma unroll
  for (int i = 0; i < 4; ++i)
    #pragma unroll
    for (int j = 0; j < 4; ++j) acc[i][j] = 0.f;

  for (int k0 = 0; k0 < 128; k0 += 64) {
    if (k0) __syncthreads();
    #pragma unroll
    for (int i = 0; i < 16; ++i) {
      int idx = tid + i * 256;
      int c2 = idx >> 6, kk = idx & 63;
      Xs[kk][c2] = Wp[(size_t)c2 * 128 + k0 + kk];
    }
    #pragma unroll
    for (int i = 0; i < 16; ++i) {
      int idx = tid + i * 256;
      int r = idx >> 6, kk = idx & 63;
      As[kk][r] = inp[(size_t)(rowbase + r) * 128 + k0 + kk];
    }
    __syncthreads();
    #pragma unroll 4
    for (int kk = 0; kk < 64; ++kk) {
      const float4 a = *(const float4*)&As[kk][r4];
      const float4 w4 = *(const float4*)&Xs[kk][cg];
      const float av[4] = {a.x, a.y, a.z, a.w};
      const float wv[4] = {w4.x, w4.y, w4.z, w4.w};
      #pragma unroll
      for (int ri = 0; ri < 4; ++ri)
        #pragma unroll
        for (int ci = 0; ci < 4; ++ci)
          acc[ri][ci] = fmaf(av[ri], wv[ci], acc[ri][ci]);
    }
  }

  float xv[4][4];
  #pragma unroll
  for (int ri = 0; ri < 4; ++ri)
    #pragma unroll
    for (int j = 0; j < 4; ++j) {
      xv[ri][j] = acc[ri][j] + bp[cg + j];
      xout[(size_t)(rowbase + r4 + ri) * CC + cg + j] = xv[ri][j];
    }

  __syncthreads();
  #pragma unroll
  for (int ri = 0; ri < 4; ++ri)
    #pragma unroll
    for (int j = 0; j < 4; ++j)
      Xs[cg + j][r4 + ri] = xv[ri][j];
  #pragma unroll
  for (int i = 0; i < 48; ++i) {
    int idx = tid + i * 256;
    int c2 = idx >> 6, kk = idx & 63;
    W2s[kk][c2] = Wqkv[(size_t)c2 * 64 + kk];
  }
  __syncthreads();

  float acc2[4][12];
  #pragma unroll
  for (int i = 0; i < 4; ++i)
    #pragma unroll
    for (int j = 0; j < 12; ++j) acc2[i][j] = 0.f;

  #pragma unroll 4
  for (int kk = 0; kk < 64; ++kk) {
    const float4 a = *(const float4*)&Xs[kk][r4];
    const float av[4] = {a.x, a.y, a.z, a.w};
    #pragma unroll
    for (int cj = 0; cj < 3; ++cj) {
      const float4 w4 = *(const float4*)&W2s[kk][cg2 + cj * 4];
      const float wv[4] = {w4.x, w4.y, w4.z, w4.w};
      #pragma unroll
      for (int ri = 0; ri < 4; ++ri)
        #pragma unroll
        for (int ci = 0; ci < 4; ++ci)
          acc2[ri][cj * 4 + ci] = fmaf(av[ri], wv[ci], acc2[ri][cj * 4 + ci]);
    }
  }

  #pragma unroll
  for (int ri = 0; ri < 4; ++ri) {
    const int row = rowbase + r4 + ri;
    const int n = row & (NN - 1);
    const int bq = (row >> 12) * NH;
    #pragma unroll
    for (int j = 0; j < 12; ++j) {
      float v = acc2[ri][j] + bqkv[cg2 + j];
      const int c2 = cg2 + j;
      const int which = c2 >> 6;         // 0=q 1=k 2=v
      const int hc = c2 & 63;
      const int bh = bq + (hc >> 4);
      const int d = hc & 15;
      if (which == 0) v *= QSCALE;
      if (which < 2)
        f16b[(size_t)which * 1048576 + ((size_t)bh * NN + n) * DH + d] = (_Float16)v;
      else
        f16b[2097152 + ((size_t)bh * DH + d) * NN + n] = (_Float16)v;
    }
  }
}

// ---------------------------------------------------------------------------
// MFMA flash attention, K-split x4, LDS-staged K/V with REGISTER PREFETCH:
// per 64-col chunk: write regs->LDS, sync, issue next chunk's loads (latency
// hides under compute), compute from LDS, sync. Single LDS buffer, 2
// barriers/chunk (same as round-10) but the vmcnt wait lands after a full
// compute phase. launch_bounds (256,6): +4 VGPR headroom, no spill.
__global__ __launch_bounds__(256, 6) void attn_k(
    const _Float16* __restrict__ qb, const _Float16* __restrict__ kb,
    const _Float16* __restrict__ vtb, float* __restrict__ po,
    float* __restrict__ rs)
{
  __shared__ _Float16 Kl[64][20];   // [k-row][d], row 40B
  __shared__ _Float16 Vl[16][72];   // [d][k-col], row 144B

  const int bid = blockIdx.x;            // 0..2047
  const int xcd = bid & 7;
  const int rest = bid >> 3;             // 0..255
  const int bh = 2 * xcd + (rest & 1);   // both bh of an XCD stay local
  const int ks = (rest >> 1) & 3;        // K-split index
  const int n0 = (rest >> 3) * 128;      // q-tile base
  const int tid = threadIdx.x;
  const int w = tid >> 6;
  const int l = tid & 63;
  const int g = l >> 4, i = l & 15;
  const int qbase = n0 + w * 32;
  const int kbeg = ks * (NN / KSPLIT);

  const _Float16* __restrict__ qhp = qb + (size_t)bh * NN * DH;
  const _Float16* __restrict__ khp = kb + (size_t)bh * NN * DH;
  const _Float16* __restrict__ vhp = vtb + (size_t)bh * DH * NN;

  const f16x4 qfA = *(const f16x4*)(qhp + (size_t)(qbase + i) * DH + 4 * g);
  const f16x4 qfB = *(const f16x4*)(qhp + (size_t)(qbase + 16 + i) * DH + 4 * g);

  f32x4 oA = {0.f, 0.f, 0.f, 0.f}, oB = {0.f, 0.f, 0.f, 0.f};
  const f32x4 zz = {0.f, 0.f, 0.f, 0.f};
  float rsA = 0.f, rsB = 0.f;

  const int srow = tid >> 2, spart = (tid & 3) * 4;  // K staging map
  const int sd = tid >> 4, scol = (tid & 15) * 4;    // V staging map

  // prologue: chunk 0 into regs (latency exposed once)
  f16x4 kr = *(const f16x4*)(khp + (size_t)(kbeg + srow) * DH + spart);
  f16x4 vr = *(const f16x4*)(vhp + (size_t)sd * NN + kbeg + scol);

  constexpr int NCH = (NN / KSPLIT) / 64;  // 16
  for (int c = 0; c < NCH; ++c) {
    // write current chunk to LDS (waits on the loads issued last iteration;
    // that wait comes AFTER a full compute phase)
    *(f16x4*)&Kl[srow][spart] = kr;
    *(f16x4*)&Vl[sd][scol] = vr;
    __syncthreads();
    if (c + 1 < NCH) {  // issue next chunk's loads; not needed until next top
      const int nx = kbeg + (c + 1) * 64;
      kr = *(const f16x4*)(khp + (size_t)(nx + srow) * DH + spart);
      vr = *(const f16x4*)(vhp + (size_t)sd * NN + nx + scol);
    }

    #pragma unroll
    for (int kk = 0; kk < 64; kk += 16) {
      const f16x4 kf = *(const f16x4*)&Kl[kk + i][4 * g];
      const f16x4 vf = *(const f16x4*)&Vl[i][kk + 4 * g];
      f32x4 sA = __builtin_amdgcn_mfma_f32_16x16x16f16(kf, qfA, zz, 0, 0, 0);
      f32x4 sB = __builtin_amdgcn_mfma_f32_16x16x16f16(kf, qfB, zz, 0, 0, 0);
      const float a0 = FAST_EXP2(sA[0]), a1 = FAST_EXP2(sA[1]),
                  a2 = FAST_EXP2(sA[2]), a3 = FAST_EXP2(sA[3]);
      const float b0 = FAST_EXP2(sB[0]), b1 = FAST_EXP2(sB[1]),
                  b2 = FAST_EXP2(sB[2]), b3 = FAST_EXP2(sB[3]);
      rsA += (a0 + a1) + (a2 + a3);
      rsB += (b0 + b1) + (b2 + b3);
      const auto alo = __builtin_amdgcn_cvt_pkrtz(a0, a1);  // __fp16 x2
      const auto ahi = __builtin_amdgcn_cvt_pkrtz(a2, a3);
      const auto blo = __builtin_amdgcn_cvt_pkrtz(b0, b1);
      const auto bhi = __builtin_amdgcn_cvt_pkrtz(b2, b3);
      f16x4 pA, pB;
      pA[0] = (_Float16)alo[0]; pA[1] = (_Float16)alo[1];
      pA[2] = (_Float16)ahi[0]; pA[3] = (_Float16)ahi[1];
      pB[0] = (_Float16)blo[0]; pB[1] = (_Float16)blo[1];
      pB[2] = (_Float16)bhi[0]; pB[3] = (_Float16)bhi[1];
      oA = __builtin_amdgcn_mfma_f32_16x16x16f16(pA, vf, oA, 0, 0, 0);
      oB = __builtin_amdgcn_mfma_f32_16x16x16f16(pB, vf, oB, 0, 0, 0);
    }
    __syncthreads();  // all reads done before next iteration's LDS write
  }

  rsA += __shfl_xor(rsA, 16); rsA += __shfl_xor(rsA, 32);
  rsB += __shfl_xor(rsB, 16); rsB += __shfl_xor(rsB, 32);

  float* __restrict__ pob = po + (size_t)(ks * 16 + bh) * NN * DH;
  #pragma unroll
  for (int r = 0; r < 4; ++r) {
    const int ql = 4 * g + r;
    pob[(size_t)(qbase + ql) * DH + i] = oA[r];
    pob[(size_t)(qbase + 16 + ql) * DH + i] = oB[r];
  }
  if (g == 0) {
    float* __restrict__ rsb = rs + (size_t)(ks * 16 + bh) * NN;
    rsb[qbase + i] = rsA;
    rsb[qbase + 16 + i] = rsB;
  }
}

// ---------------------------------------------------------------------------
// Wo GEMM with fused K-split reduction + residual (round-10 known-good).
// po ks-stride = 1048576 floats; rs ks-stride = 65536 floats.
__global__ __launch_bounds__(256) void wo_red_k(
    const float* __restrict__ po, const float* __restrict__ rs,
    const float* __restrict__ Wo, const float* __restrict__ bo,
    const float* __restrict__ xin, float* __restrict__ out)
{
  __shared__ __align__(16) float As[64][68];
  __shared__ __align__(16) float Ws[64][68];
  __shared__ float Linv[64][4];

  const int tid = threadIdx.x;
  const int rowbase = blockIdx.x * 64;
  const int r4 = (tid & 15) * 4;
  const int cg = (tid >> 4) * 4;

  {
    const int r = tid & 63, hb = tid >> 6;
    const int row = rowbase + r;
    const int bh = (row >> 12) * NH + hb;
    const int n = row & (NN - 1);
    const float s = rs[(size_t)bh * NN + n] + rs[(size_t)(16 + bh) * NN + n] +
                    rs[(size_t)(32 + bh) * NN + n] + rs[(size_t)(48 + bh) * NN + n];
    Linv[r][hb] = 1.f / s;
  }
  #pragma unroll
  for (int i = 0; i < 16; ++i) {
    int idx = tid + i * 256;
    int c2 = idx >> 6, kk = idx & 63;
    Ws[kk][c2] = Wo[(size_t)c2 * 64 + kk];
  }
  __syncthreads();
  #pragma unroll
  for (int i = 0; i < 16; ++i) {
    int idx = tid + i * 256;
    int r = idx >> 6, kk = idx & 63;
    const int row = rowbase + r;
    const int bh = (row >> 12) * NH + (kk >> 4);
    const int n = row & (NN - 1);
    const int d = kk & 15;
    const size_t base = (((size_t)bh * NN + n) * DH) + d;
    const float v = po[base] + po[base + 1048576] +
                    po[base + 2097152] + po[base + 3145728];
    As[kk][r] = v * Linv[r][kk >> 4];
  }
  __syncthreads();

  float acc[4][4];
  #pragma unroll
  for (int i = 0; i < 4; ++i)
    #pragma unroll
    for (int j = 0; j < 4; ++j) acc[i][j] = 0.f;

  #pragma unroll 4
  for (int kk = 0; kk < 64; ++kk) {
    const float4 a = *(const float4*)&As[kk][r4];
    const float4 w4 = *(const float4*)&Ws[kk][cg];
    const float av[4] = {a.x, a.y, a.z, a.w};
    const float wv[4] = {w4.x, w4.y, w4.z, w4.w};
    #pragma unroll
    for (int ri = 0; ri < 4; ++ri)
      #pragma unroll
      for (int ci = 0; ci < 4; ++ci)
        acc[ri][ci] = fmaf(av[ri], wv[ci], acc[ri][ci]);
  }

  #pragma unroll
  for (int ri = 0; ri < 4; ++ri) {
    const int row = rowbase + r4 + ri;
    #pragma unroll
    for (int j = 0; j < 4; ++j) {
      const int c = cg + j;
      out[(size_t)row * CC + c] =
          acc[ri][j] + bo[c] + xin[(size_t)row * CC + c];
    }
  }
}

// ---------------------------------------------------------------------------
// Fused MLP (round-10 known-good): t = relu(h @ W1^T + b1) in LDS,
// pre3 = t @ W2^T + b2m + h.
__global__ __launch_bounds__(256) void mlp_k(
    const float* __restrict__ hf, const float* __restrict__ W1,
    const float* __restrict__ b1, const float* __restrict__ W2,
    const float* __restrict__ b2m, float* __restrict__ out)
{
  __shared__ __align__(16) float As[64][68];
  __shared__ __align__(16) float Wbuf[8704];
  __shared__ __align__(16) float Ts[128][68];

  const int tid = threadIdx.x;
  const int rowbase = blockIdx.x * 64;
  const int r4 = (tid & 15) * 4;
  const int cg8 = (tid >> 4) * 8;
  const int cg4 = (tid >> 4) * 4;

  #pragma unroll
  for (int i = 0; i < 32; ++i) {
    int idx = tid + i * 256;
    int c2 = idx >> 6, kk = idx & 63;
    Wbuf[kk * 132 + c2] = W1[(size_t)c2 * 64 + kk];
  }
  #pragma unroll
  for (int i = 0; i < 16; ++i) {
    int idx = tid + i * 256;
    int r = idx >> 6, kk = idx & 63;
    As[kk][r] = hf[(size_t)(rowbase + r) * CC + kk];
  }
  __syncthreads();

  float acc1[4][8];
  #pragma unroll
  for (int i = 0; i < 4; ++i)
    #pragma unroll
    for (int j = 0; j < 8; ++j) acc1[i][j] = 0.f;

  #pragma unroll 4
  for (int kk = 0; kk < 64; ++kk) {
    const float4 a = *(const float4*)&As[kk][r4];
    const float av[4] = {a.x, a.y, a.z, a.w};
    #pragma unroll
    for (int cj = 0; cj < 2; ++cj) {
      const float4 w4 = *(const float4*)&Wbuf[kk * 132 + cg8 + cj * 4];
      const float wv[4] = {w4.x, w4.y, w4.z, w4.w};
      #pragma unroll
      for (int ri = 0; ri < 4; ++ri)
        #pragma unroll
        for (int ci = 0; ci < 4; ++ci)
          acc1[ri][cj * 4 + ci] = fmaf(av[ri], wv[ci], acc1[ri][cj * 4 + ci]);
    }
  }
  #pragma unroll
  for (int ri = 0; ri < 4; ++ri)
    #pragma unroll
    for (int j = 0; j < 8; ++j)
      Ts[cg8 + j][r4 + ri] = fmaxf(acc1[ri][j] + b1[cg8 + j], 0.f);
  __syncthreads();

  #pragma unroll
  for (int i = 0; i < 32; ++i) {
    int idx = tid + i * 256;
    int c2 = idx >> 7, kk = idx & 127;
    Wbuf[kk * 68 + c2] = W2[(size_t)c2 * 128 + kk];
  }
  __syncthreads();

  float acc2[4][4];
  #pragma unroll
  for (int i = 0; i < 4; ++i)
    #pragma unroll
    for (int j = 0; j < 4; ++j) acc2[i][j] = 0.f;

  #pragma unroll 4
  for (int kk = 0; kk < 128; ++kk) {
    const float4 a = *(const float4*)&Ts[kk][r4];
    const float4 w4 = *(const float4*)&Wbuf[kk * 68 + cg4];
    const float av[4] = {a.x, a.y, a.z, a.w};
    const float wv[4] = {w4.x, w4.y, w4.z, w4.w};
    #pragma unroll
    for (int ri = 0; ri < 4; ++ri)
      #pragma unroll
      for (int ci = 0; ci < 4; ++ci)
        acc2[ri][ci] = fmaf(av[ri], wv[ci], acc2[ri][ci]);
  }

  #pragma unroll
  for (int ri = 0; ri < 4; ++ri) {
    const int row = rowbase + r4 + ri;
    #pragma unroll
    for (int j = 0; j < 4; ++j) {
      const int c = cg4 + j;
      out[(size_t)row * CC + c] = acc2[ri][j] + b2m[c] + As[c][r4 + ri];
    }
  }
}

// ---------------------------------------------------------------------------
// BatchNorm over node axis, 4 channels per block (float4), biased var,
// EPS=1e-5, optional fused tanh. Grid 64. In-place safe.
__global__ __launch_bounds__(256) void bn4_k(
    const float* __restrict__ in, const float* __restrict__ g,
    const float* __restrict__ b, float* __restrict__ out, int do_tanh)
{
  const int bb = blockIdx.x >> 4;
  const int c4 = (blockIdx.x & 15) * 4;
  const float* __restrict__ base = in + (size_t)bb * NN * CC + c4;
  const int tid = threadIdx.x;

  float4 s = {0, 0, 0, 0}, sq = {0, 0, 0, 0};
  #pragma unroll
  for (int i = 0; i < 16; ++i) {
    const float4 v = *(const float4*)&base[(size_t)(tid + i * 256) * CC];
    s.x += v.x; s.y += v.y; s.z += v.z; s.w += v.w;
    sq.x = fmaf(v.x, v.x, sq.x); sq.y = fmaf(v.y, v.y, sq.y);
    sq.z = fmaf(v.z, v.z, sq.z); sq.w = fmaf(v.w, v.w, sq.w);
  }
  #pragma unroll
  for (int off = 32; off; off >>= 1) {
    s.x += __shfl_down(s.x, off); s.y += __shfl_down(s.y, off);
    s.z += __shfl_down(s.z, off); s.w += __shfl_down(s.w, off);
    sq.x += __shfl_down(sq.x, off); sq.y += __shfl_down(sq.y, off);
    sq.z += __shfl_down(sq.z, off); sq.w += __shfl_down(sq.w, off);
  }
  __shared__ float red[4][8];
  const int wv = tid >> 6;
  if ((tid & 63) == 0) {
    red[wv][0] = s.x; red[wv][1] = s.y; red[wv][2] = s.z; red[wv][3] = s.w;
    red[wv][4] = sq.x; red[wv][5] = sq.y; red[wv][6] = sq.z; red[wv][7] = sq.w;
  }
  __syncthreads();
  float scale[4], shift[4];
  #pragma unroll
  for (int j = 0; j < 4; ++j) {
    const float ts = red[0][j] + red[1][j] + red[2][j] + red[3][j];
    const float tq = red[0][4 + j] + red[1][4 + j] + red[2][4 + j] + red[3][4 + j];
    const float mean = ts * (1.f / NN);
    const float var = tq * (1.f / NN) - mean * mean;
    const float rstd = rsqrtf(var + 1e-5f);
    scale[j] = g[c4 + j] * rstd;
    shift[j] = b[c4 + j] - mean * scale[j];
  }
  float* __restrict__ ob = out + (size_t)bb * NN * CC + c4;
  #pragma unroll
  for (int i = 0; i < 16; ++i) {
    const size_t idx = (size_t)(tid + i * 256) * CC;
    const float4 v = *(const float4*)&base[idx];
    float4 o;
    o.x = v.x * scale[0] + shift[0];
    o.y = v.y * scale[1] + shift[1];
    o.z = v.z * scale[2] + shift[2];
    o.w = v.w * scale[3] + shift[3];
    if (do_tanh) {
      o.x = fast_tanh(o.x); o.y = fast_tanh(o.y);
      o.z = fast_tanh(o.z); o.w = fast_tanh(o.w);
    }
    *(float4*)&ob[idx] = o;
  }
}

// ---------------------------------------------------------------------------
extern "C" void kernel_launch(void* const* d_in, const int* in_sizes, int n_in,
                              void* d_out, int out_size, void* d_ws, size_t ws_size,
                              hipStream_t stream)
{
  const float* inp  = (const float*)d_in[0];
  const float* Wp   = (const float*)d_in[2];
  const float* bp   = (const float*)d_in[3];
  const float* Wqkv = (const float*)d_in[4];
  const float* bqkv = (const float*)d_in[5];
  const float* Wo   = (const float*)d_in[6];
  const float* bo   = (const float*)d_in[7];
  const float* g2   = (const float*)d_in[8];
  const float* b2   = (const float*)d_in[9];
  const float* W1   = (const float*)d_in[10];
  const float* b1   = (const float*)d_in[11];
  const float* W2   = (const float*)d_in[12];
  const float* b2m  = (const float*)d_in[13];
  const float* g3   = (const float*)d_in[14];
  const float* b3   = (const float*)d_in[15];

  float* w = (float*)d_ws;
  float* x    = w;                 // [16384][64]   (dead after wo_red)
  float* qkvA = w + 1048576;       // f16 arena: q 0..1M, k 1M..2M, vt 2M..3M halves
  float* hf   = w + 2621440;       // pre2 -> (in-place bn) h
  float* pf   = w + 3670016;       // pre3 = h + mlp
  float* poW  = w + 4718592;       // attn partial O [4][16][4096][16]
  float* rsW  = w + 8912896;       // attn partial rowsums [4][16][4096]

  _Float16* f16b = (_Float16*)qkvA;

  proj_qkv_k<<<dim3(256), dim3(256), 0, stream>>>(inp, Wp, bp, Wqkv, bqkv, x, f16b);
  attn_k<<<dim3(2048), dim3(256), 0, stream>>>(f16b, f16b + 1048576,
                                               f16b + 2097152, poW, rsW);
  wo_red_k<<<dim3(256), dim3(256), 0, stream>>>(poW, rsW, Wo, bo, x, hf);
  bn4_k<<<dim3(64), dim3(256), 0, stream>>>(hf, g2, b2, hf, 0);
  mlp_k<<<dim3(256), dim3(256), 0, stream>>>(hf, W1, b1, W2, b2m, pf);
  bn4_k<<<dim3(64), dim3(256), 0, stream>>>(pf, g3, b3, (float*)d_out, 1);
}